// Round 7
// baseline (712.920 us; speedup 1.0000x reference)
//
#include <hip/hip_runtime.h>
#include <hip/hip_bf16.h>
#include <type_traits>

// ---------------------------------------------------------------------------
// PerceiverAttention on MI355X.
// Pipeline (4 launches):
//   1) prep_kernel   : [fused] Wkv/Wq/Wo transposes AND LayerNorm -> ctx/qin
//   2) gemm_kvq      : [fused] kv = ctx @ WkvT^T (4128 blk, T1 swizzle) AND
//                      q = 0.125 * (qin @ WqT^T) (16 blk in tail; the 2^-3
//                      scale folded here is EXACT in bf16 -> attn drops its
//                      per-element scale, bit-identical S). Also zeroes the
//                      attn split counters.
//   3) attn_flash    : split-K MFMA flash attention, wave-local softmax,
//                      T14 V-reg-prefetch (next tile's V loads issued under
//                      current tile's compute), FUSED split-combine: last
//                      block per comb (device atomic) merges the 16 partials
//                      with agent-scope loads (Op/ml alias ctx -> stale-L2
//                      bypass required) -> outp bf16 [512][512].
//   4) gemm_bt<float>: out = outp @ WoT^T -> f32 d_out [512][768]
// History: three 256^2 deep-pipeline ports (R1 185/R2 169/R4 206us) lost to
// the 128^2 m97 kernel (156us) at K=768 (12 K-tiles). KV GEMM loop frozen.
// ---------------------------------------------------------------------------

#define N_SRC 8192
#define N_LTN 64
#define N_CTX 8256            // per (b,t)
#define NBT 8                 // b*t
#define MROWS 66048           // NBT * N_CTX
#define DIMK 768
#define DEMB 512
#define NSPLIT 16
#define NTILES 65             // ceil(N_CTX / 128)

#define LN_BLOCKS (MROWS / 4)     // 16512
#define TR_BLOCKS 576             // 16 x 12 x 3
#define KV_BLOCKS 4128            // 8 x 516
#define Q_BLOCKS  16              // 4 x 4

typedef short short8 __attribute__((ext_vector_type(8)));
typedef float floatx4 __attribute__((ext_vector_type(4)));
typedef __attribute__((address_space(1))) void gvoid;
typedef __attribute__((address_space(3))) void lvoid;

__device__ inline ushort f2bf(float f) {
    union { float f; unsigned u; } v; v.f = f;
    unsigned u = v.u;
    return (ushort)((u + 0x7fffu + ((u >> 16) & 1u)) >> 16);   // RNE
}

// agent-scope (device-coherent) f32 load: bypasses per-XCD L2 that may hold
// stale clean copies (Op/ml alias ctx, which every XCD cached in gemm_kvq).
__device__ inline float ldag(const float* p) {
    unsigned u = __hip_atomic_load((const unsigned*)p, __ATOMIC_RELAXED,
                                   __HIP_MEMORY_SCOPE_AGENT);
    union { unsigned u; float f; } c; c.u = u;
    return c.f;
}

// ------------------- prep: weight transposes + layernorm -------------------
__global__ __launch_bounds__(256) void prep_kernel(
        const float* __restrict__ src, const float* __restrict__ ltn,
        const float* __restrict__ gs, const float* __restrict__ bs,
        const float* __restrict__ gl, const float* __restrict__ bl,
        ushort* __restrict__ ctx, ushort* __restrict__ qin,
        const float* __restrict__ Wkv, const float* __restrict__ Wq,
        const float* __restrict__ Wo, ushort* __restrict__ WkvT,
        ushort* __restrict__ WqT, ushort* __restrict__ WoT) {
    __shared__ ushort tile[64][65];
    int bid = blockIdx.x;

    if (bid < LN_BLOCKS) {
        // ---------------- layernorm ----------------
        int r = bid * 4 + (threadIdx.x >> 6);
        int lane = threadIdx.x & 63;
        int bt = r / N_CTX;
        int i = r - bt * N_CTX;
        const float *x, *g, *b;
        int isl = (i >= N_SRC);
        if (!isl) { x = src + ((size_t)bt * N_SRC + i) * DIMK; g = gs; b = bs; }
        else      { x = ltn + ((size_t)bt * N_LTN + (i - N_SRC)) * DIMK; g = gl; b = bl; }
        float4 v[3]; float s = 0.f, s2 = 0.f;
#pragma unroll
        for (int t = 0; t < 3; t++) {
            float4 xv = *(const float4*)(x + t * 256 + lane * 4);
            v[t] = xv;
            s  += xv.x + xv.y + xv.z + xv.w;
            s2 += xv.x * xv.x + xv.y * xv.y + xv.z * xv.z + xv.w * xv.w;
        }
#pragma unroll
        for (int off = 32; off >= 1; off >>= 1) {
            s  += __shfl_xor(s,  off, 64);
            s2 += __shfl_xor(s2, off, 64);
        }
        float mu  = s * (1.0f / 768.0f);
        float var = s2 * (1.0f / 768.0f) - mu * mu;
        float rs  = rsqrtf(var + 1e-5f);
        ushort* crow = ctx + (size_t)r * DIMK;
        ushort* qrow = isl ? (qin + (size_t)(bt * N_LTN + (i - N_SRC)) * DIMK) : nullptr;
#pragma unroll
        for (int t = 0; t < 3; t++) {
            int idx = t * 256 + lane * 4;
            float4 gv = *(const float4*)(g + idx);
            float4 bv = *(const float4*)(b + idx);
            ushort4 u;
            u.x = f2bf((v[t].x - mu) * rs * gv.x + bv.x);
            u.y = f2bf((v[t].y - mu) * rs * gv.y + bv.y);
            u.z = f2bf((v[t].z - mu) * rs * gv.z + bv.z);
            u.w = f2bf((v[t].w - mu) * rs * gv.w + bv.w);
            *(ushort4*)(crow + idx) = u;
            if (isl) *(ushort4*)(qrow + idx) = u;
        }
        return;
    }

    // ---------------- weight transpose ----------------
    int bid2 = bid - LN_BLOCKS;          // [0, 576): x 16, y 12, z 3
    int z = bid2 / 192;
    int rem = bid2 - z * 192;
    int by = rem >> 4, bx = rem & 15;
    const float* in; ushort* out; int R, C;
    if (z == 0)      { in = Wkv; out = WkvT; R = 768; C = 1024; }
    else if (z == 1) { in = Wq;  out = WqT;  R = 768; C = 512;  }
    else             { in = Wo;  out = WoT;  R = 512; C = 768;  }
    int C0 = bx * 64, R0 = by * 64;
    if (C0 >= C || R0 >= R) return;      // uniform early-out (before any sync)
    int tc = threadIdx.x & 63, tr4 = threadIdx.x >> 6;
#pragma unroll
    for (int j = 0; j < 16; j++) {
        int r = tr4 + j * 4;
        tile[r][tc] = f2bf(in[(size_t)(R0 + r) * C + C0 + tc]);
    }
    __syncthreads();
#pragma unroll
    for (int j = 0; j < 16; j++) {
        int c = tr4 + j * 4;
        out[(size_t)(C0 + c) * R + R0 + tc] = tile[tc][c];
    }
}

// --------------- fused KV + Q projection GEMM (128^2, K=768) ---------------
// blocks [0, KV_BLOCKS)        : kvb[66048][1024] = ctx @ WkvT^T, T1 swizzle
// blocks [KV_BLOCKS, +Q_BLOCKS): qfb[512][512] = 0.125*(qin @ WqT^T) (tail)
// Single bf16 epilogue path; scl is SGPR-uniform {1.0, 0.125} (x1.0 exact).
// Block KV_BLOCKS additionally zeroes the 64 attn split counters.
__global__ __launch_bounds__(256) void gemm_kvq(
        const ushort* __restrict__ ctx, const ushort* __restrict__ WkvT,
        ushort* __restrict__ kvb, const ushort* __restrict__ qin,
        const ushort* __restrict__ WqT, ushort* __restrict__ qfb,
        int* __restrict__ cnt) {
    __shared__ ushort lA[128 * 64];
    __shared__ ushort lB[128 * 64];
    int tid = threadIdx.x;
    int lane = tid & 63, wave = tid >> 6;
    int wm = wave >> 1, wn = wave & 1;

    int lin = blockIdx.x;
    const ushort *A, *B;
    ushort* Cp;
    int bm, bn, N;
    float scl;
    if (lin < KV_BLOCKS) {
        int swz = (lin & 7) * (KV_BLOCKS >> 3) + (lin >> 3);   // T1, 4128%8==0
        bn = swz & 7; bm = swz >> 3;                           // 8 col-tiles
        A = ctx; B = WkvT; Cp = kvb; N = 1024; scl = 1.0f;
    } else {
        if (lin == KV_BLOCKS && tid < 64) cnt[tid] = 0;        // attn counters
        int l2 = lin - KV_BLOCKS;
        bn = l2 & 3; bm = l2 >> 2;                             // 4 x 4
        A = qin; B = WqT; Cp = qfb; N = 512; scl = 0.125f;     // exact 2^-3
    }
    const int K = DIMK;                                        // 768 for both

    floatx4 acc[4][4];
#pragma unroll
    for (int mi = 0; mi < 4; mi++)
#pragma unroll
        for (int ni = 0; ni < 4; ni++) acc[mi][ni] = (floatx4){0.f, 0.f, 0.f, 0.f};

    int srow = lane >> 3;
    int schunk = (lane & 7) ^ srow;
    int quad = lane >> 4, lr = lane & 15;
    const int kiters = K >> 6;                                 // 12

    for (int kt = 0; kt < kiters; kt++) {
#pragma unroll
        for (int c2 = 0; c2 < 4; c2++) {
            int row = c2 * 32 + wave * 8 + srow;
            const ushort* gpA = A + ((size_t)(bm * 128 + row) * K + kt * 64 + schunk * 8);
            ushort* lpA = lA + (c2 * 32 + wave * 8) * 64 + lane * 8;
            __builtin_amdgcn_global_load_lds((gvoid*)gpA, (lvoid*)lpA, 16, 0, 0);
            const ushort* gpB = B + ((size_t)(bn * 128 + row) * K + kt * 64 + schunk * 8);
            ushort* lpB = lB + (c2 * 32 + wave * 8) * 64 + lane * 8;
            __builtin_amdgcn_global_load_lds((gvoid*)gpB, (lvoid*)lpB, 16, 0, 0);
        }
        __syncthreads();
#pragma unroll
        for (int ks = 0; ks < 2; ks++) {
            short8 av[4], bv[4];
            int slot = ((ks * 4 + quad) ^ (lane & 7)) * 8;
#pragma unroll
            for (int mi = 0; mi < 4; mi++)
                av[mi] = *(const short8*)(lA + (wm * 64 + mi * 16 + lr) * 64 + slot);
#pragma unroll
            for (int ni = 0; ni < 4; ni++)
                bv[ni] = *(const short8*)(lB + (wn * 64 + ni * 16 + lr) * 64 + slot);
#pragma unroll
            for (int mi = 0; mi < 4; mi++)
#pragma unroll
                for (int ni = 0; ni < 4; ni++)
                    acc[mi][ni] = __builtin_amdgcn_mfma_f32_16x16x32_bf16(
                        av[mi], bv[ni], acc[mi][ni], 0, 0, 0);
        }
        __syncthreads();
    }
#pragma unroll
    for (int mi = 0; mi < 4; mi++)
#pragma unroll
        for (int ni = 0; ni < 4; ni++)
#pragma unroll
            for (int r = 0; r < 4; r++) {
                int row = bm * 128 + wm * 64 + mi * 16 + quad * 4 + r;
                int col = bn * 128 + wn * 64 + ni * 16 + lr;
                Cp[(size_t)row * N + col] = f2bf(acc[mi][ni][r] * scl);
            }
}

// ------------------------------- GEMM (128^2) ------------------------------
// Used for the Wo projection (grid 24, 24%8==0 for T1).
template <typename CT>
__global__ __launch_bounds__(256) void gemm_bt(
        const ushort* __restrict__ A, const ushort* __restrict__ B,
        CT* __restrict__ C, int M, int N, int K) {
    __shared__ ushort lA[128 * 64];
    __shared__ ushort lB[128 * 64];
    int tid = threadIdx.x;
    int lane = tid & 63, wave = tid >> 6;
    int wm = wave >> 1, wn = wave & 1;

    int nwg = gridDim.x * gridDim.y;
    int lin = blockIdx.y * gridDim.x + blockIdx.x;
    int swz = (lin & 7) * (nwg >> 3) + (lin >> 3);
    int bn = swz % gridDim.x, bm = swz / gridDim.x;

    floatx4 acc[4][4];
#pragma unroll
    for (int mi = 0; mi < 4; mi++)
#pragma unroll
        for (int ni = 0; ni < 4; ni++) acc[mi][ni] = (floatx4){0.f, 0.f, 0.f, 0.f};

    int srow = lane >> 3;
    int schunk = (lane & 7) ^ srow;
    int quad = lane >> 4, lr = lane & 15;
    const int kiters = K >> 6;

    for (int kt = 0; kt < kiters; kt++) {
#pragma unroll
        for (int c2 = 0; c2 < 4; c2++) {
            int row = c2 * 32 + wave * 8 + srow;
            const ushort* gpA = A + ((size_t)(bm * 128 + row) * K + kt * 64 + schunk * 8);
            ushort* lpA = lA + (c2 * 32 + wave * 8) * 64 + lane * 8;
            __builtin_amdgcn_global_load_lds((gvoid*)gpA, (lvoid*)lpA, 16, 0, 0);
            const ushort* gpB = B + ((size_t)(bn * 128 + row) * K + kt * 64 + schunk * 8);
            ushort* lpB = lB + (c2 * 32 + wave * 8) * 64 + lane * 8;
            __builtin_amdgcn_global_load_lds((gvoid*)gpB, (lvoid*)lpB, 16, 0, 0);
        }
        __syncthreads();
#pragma unroll
        for (int ks = 0; ks < 2; ks++) {
            short8 av[4], bv[4];
            int slot = ((ks * 4 + quad) ^ (lane & 7)) * 8;
#pragma unroll
            for (int mi = 0; mi < 4; mi++)
                av[mi] = *(const short8*)(lA + (wm * 64 + mi * 16 + lr) * 64 + slot);
#pragma unroll
            for (int ni = 0; ni < 4; ni++)
                bv[ni] = *(const short8*)(lB + (wn * 64 + ni * 16 + lr) * 64 + slot);
#pragma unroll
            for (int mi = 0; mi < 4; mi++)
#pragma unroll
                for (int ni = 0; ni < 4; ni++)
                    acc[mi][ni] = __builtin_amdgcn_mfma_f32_16x16x32_bf16(
                        av[mi], bv[ni], acc[mi][ni], 0, 0, 0);
        }
        __syncthreads();
    }
#pragma unroll
    for (int mi = 0; mi < 4; mi++)
#pragma unroll
        for (int ni = 0; ni < 4; ni++)
#pragma unroll
            for (int r = 0; r < 4; r++) {
                int row = bm * 128 + wm * 64 + mi * 16 + quad * 4 + r;
                int col = bn * 128 + wn * 64 + ni * 16 + lr;
                float vv = acc[mi][ni][r];
                if constexpr (std::is_same<CT, ushort>::value)
                    C[(size_t)row * N + col] = f2bf(vv);
                else
                    C[(size_t)row * N + col] = vv;
            }
}

// ------------------ flash attention (split-K, fused combine) ---------------
// Wave-local softmax (wave w owns rows w*16..+16). Q arrives pre-scaled by
// 0.125 (exact) so S needs no per-element scale; the masked S overwrites
// accS in place (saves the 32-reg sc[] array, funding the V-prefetch regs).
// T14: next tile's V is loaded to regs right after the staging barrier, so
// its HBM latency hides under QK^T+softmax+PV. Tail masking is a pure-ALU
// lane mask applied at unpack (no vmcnt stall at load site).
// Split-combine fused: stores -> __threadfence -> atomicAdd(cnt[comb]); the
// 16th block merges all partials with agent-scope loads (stale-L2 bypass).
#define PR 136

__global__ __launch_bounds__(256) void attn_flash(
        const ushort* __restrict__ qfb, const ushort* __restrict__ kvb,
        float* __restrict__ Op, float* __restrict__ ml,
        int* __restrict__ cnt, ushort* __restrict__ outp) {
    __shared__ ushort lK[128 * 64];
    __shared__ ushort lVT[64 * PR];   // [d 0..63][key 0..127]
    __shared__ ushort lP[64 * PR];    // [qrow 0..63][key 0..127], wave-private rows
    __shared__ int sLast;

    int comb = blockIdx.x, split = blockIdx.y;
    int bt = comb >> 3, h = comb & 7;
    int tid = threadIdx.x;
    int w = tid >> 6, lane = tid & 63, quad = lane >> 4, lr = lane & 15;

    const ushort* kptr = kvb + (size_t)bt * N_CTX * 1024 + h * 64;
    const ushort* vptr = kptr + 512;

    short8 qa[2];
    {
        const ushort* p0 = qfb + (size_t)(bt * 64 + w * 16 + lr) * DEMB + h * 64;
        qa[0] = *(const short8*)(p0 + quad * 8);
        qa[1] = *(const short8*)(p0 + 32 + quad * 8);
    }

    floatx4 accO[4];
#pragma unroll
    for (int nt = 0; nt < 4; nt++) accO[nt] = (floatx4){0.f, 0.f, 0.f, 0.f};
    float m_run[4], l_run[4];
#pragma unroll
    for (int r = 0; r < 4; r++) { m_run[r] = -1e30f; l_run[r] = 0.f; }

    // ---- V reg-prefetch state (tile whose V currently sits in vreg) ----
    uint4 vreg[4];
    unsigned vmask;
    auto loadV = [&](int t) {
        int k0 = t * 128 + lane * 2;
        bool valid = (k0 + 1) < N_CTX;
        int k0c = valid ? k0 : (N_CTX - 2);
        const ushort* r0 = vptr + (size_t)k0c * 1024 + w * 16;
        vreg[0] = *(const uint4*)r0;
        vreg[1] = *(const uint4*)(r0 + 8);
        vreg[2] = *(const uint4*)(r0 + 1024);
        vreg[3] = *(const uint4*)(r0 + 1032);
        vmask = valid ? 0xffffffffu : 0u;   // ALU-only; applied at unpack
    };
    loadV(split);

    for (int t = split; t < NTILES; t += NSPLIT) {
        int kbase = t * 128;
        __syncthreads();   // prev-iter lK/lVT readers done before restaging

        // ---- stage K (global_load_lds, swizzled) ----
#pragma unroll
        for (int c2 = 0; c2 < 4; c2++) {
            int jloc = w * 32 + c2 * 8 + (lane >> 3);
            int chunk = (lane & 7) ^ ((lane >> 3) & 7);
            int jg = kbase + jloc; if (jg > N_CTX - 1) jg = N_CTX - 1;  // clamp tail
            const ushort* gp = kptr + (size_t)jg * 1024 + chunk * 8;
            ushort* lp = lK + (w * 32 + c2 * 8) * 64 + lane * 8;
            __builtin_amdgcn_global_load_lds((gvoid*)gp, (lvoid*)lp, 16, 0, 0);
        }

        // ---- unpack held V regs -> lVT (pack-transpose) ----
        {
            unsigned av8[8] = {vreg[0].x & vmask, vreg[0].y & vmask,
                               vreg[0].z & vmask, vreg[0].w & vmask,
                               vreg[1].x & vmask, vreg[1].y & vmask,
                               vreg[1].z & vmask, vreg[1].w & vmask};
            unsigned bv8[8] = {vreg[2].x & vmask, vreg[2].y & vmask,
                               vreg[2].z & vmask, vreg[2].w & vmask,
                               vreg[3].x & vmask, vreg[3].y & vmask,
                               vreg[3].z & vmask, vreg[3].w & vmask};
#pragma unroll
            for (int i = 0; i < 8; i++) {
                unsigned la = av8[i] & 0xffffu, ha = av8[i] >> 16;
                unsigned lb = bv8[i] & 0xffffu, hb = bv8[i] >> 16;
                *(unsigned*)(lVT + (w * 16 + 2 * i) * PR + lane * 2)     = la | (lb << 16);
                *(unsigned*)(lVT + (w * 16 + 2 * i + 1) * PR + lane * 2) = ha | (hb << 16);
            }
        }
        __syncthreads();   // staging complete

        // ---- prefetch next tile's V under this tile's compute (T14) ----
        int tn = t + NSPLIT;
        if (tn < NTILES) loadV(tn);

        floatx4 accS[8];
#pragma unroll
        for (int nt = 0; nt < 8; nt++) accS[nt] = (floatx4){0.f, 0.f, 0.f, 0.f};
#pragma unroll
        for (int kc = 0; kc < 2; kc++) {
#pragma unroll
            for (int nt = 0; nt < 8; nt++) {
                int kr = nt * 16 + lr;
                int slot = (kc * 4 + quad) ^ (kr & 7);
                short8 bv = *(const short8*)(lK + kr * 64 + slot * 8);
                accS[nt] = __builtin_amdgcn_mfma_f32_16x16x32_bf16(
                    qa[kc], bv, accS[nt], 0, 0, 0);
            }
        }

        // ---- mask (in place) + row max ----
        float tmax[4] = {-1e30f, -1e30f, -1e30f, -1e30f};
#pragma unroll
        for (int nt = 0; nt < 8; nt++) {
            bool vk = (kbase + nt * 16 + lr) < N_CTX;
#pragma unroll
            for (int r = 0; r < 4; r++) {
                float s = vk ? accS[nt][r] : -1e30f;
                accS[nt][r] = s;
                tmax[r] = fmaxf(tmax[r], s);
            }
        }
#pragma unroll
        for (int r = 0; r < 4; r++) {
#pragma unroll
            for (int d = 1; d < 16; d <<= 1) tmax[r] = fmaxf(tmax[r], __shfl_xor(tmax[r], d, 64));
        }
        float alpha[4], lsum[4];
#pragma unroll
        for (int r = 0; r < 4; r++) {
            float mn = fmaxf(m_run[r], tmax[r]);
            alpha[r] = __expf(m_run[r] - mn);
            m_run[r] = mn;
            lsum[r] = 0.f;
        }

#pragma unroll
        for (int nt = 0; nt < 8; nt++) {
#pragma unroll
            for (int r = 0; r < 4; r++) {
                float p = __expf(accS[nt][r] - m_run[r]);
                lsum[r] += p;
                lP[(w * 16 + quad * 4 + r) * PR + nt * 16 + lr] = f2bf(p);
            }
        }
#pragma unroll
        for (int r = 0; r < 4; r++) {
#pragma unroll
            for (int d = 1; d < 16; d <<= 1) lsum[r] += __shfl_xor(lsum[r], d, 64);
            l_run[r] = l_run[r] * alpha[r] + lsum[r];
        }
#pragma unroll
        for (int nt = 0; nt < 4; nt++) {
            accO[nt][0] *= alpha[0]; accO[nt][1] *= alpha[1];
            accO[nt][2] *= alpha[2]; accO[nt][3] *= alpha[3];
        }

        short8 av[4];
#pragma unroll
        for (int kc = 0; kc < 4; kc++)
            av[kc] = *(const short8*)(lP + (w * 16 + lr) * PR + kc * 32 + quad * 8);
#pragma unroll
        for (int nt = 0; nt < 4; nt++)
#pragma unroll
            for (int kc = 0; kc < 4; kc++) {
                short8 bv = *(const short8*)(lVT + (nt * 16 + lr) * PR + kc * 32 + quad * 8);
                accO[nt] = __builtin_amdgcn_mfma_f32_16x16x32_bf16(av[kc], bv, accO[nt], 0, 0, 0);
            }
    }

    // ---- store partials ----
    float* opb = Op + (size_t)(comb * NSPLIT + split) * 64 * 64;
#pragma unroll
    for (int nt = 0; nt < 4; nt++)
#pragma unroll
        for (int r = 0; r < 4; r++)
            opb[(w * 16 + quad * 4 + r) * 64 + nt * 16 + lr] = accO[nt][r];
    if (lr == 0) {
#pragma unroll
        for (int r = 0; r < 4; r++) {
            int row = w * 16 + quad * 4 + r;
            float* mlp = ml + ((size_t)(comb * NSPLIT + split) * 64 + row) * 2;
            mlp[0] = m_run[r]; mlp[1] = l_run[r];
        }
    }

    // ---- fused combine: last block of this comb merges the 16 splits ----
    __threadfence();                       // device-scope release of Op/ml
    if (tid == 0)
        sLast = (atomicAdd(&cnt[comb], 1) == NSPLIT - 1);
    __syncthreads();
    if (sLast) {
        int q = tid >> 2, dg = tid & 3;    // 64 q x 4 d-groups of 16
        const float* mlc = ml + ((size_t)(comb * NSPLIT) * 64 + q) * 2;
        float M = -1e30f;
        for (int s = 0; s < NSPLIT; s++)
            M = fmaxf(M, ldag(mlc + s * 128));
        float L = 0.f;
        float O[16];
#pragma unroll
        for (int j = 0; j < 16; j++) O[j] = 0.f;
        for (int s = 0; s < NSPLIT; s++) {
            float m0 = ldag(mlc + s * 128);
            float l0 = ldag(mlc + s * 128 + 1);
            float wgt = __expf(m0 - M);
            L = fmaf(wgt, l0, L);
            const float* ob = Op + ((size_t)(comb * NSPLIT + s) * 64 + q) * 64 + dg * 16;
#pragma unroll
            for (int j = 0; j < 16; j++) O[j] = fmaf(wgt, ldag(ob + j), O[j]);
        }
        ushort* op = outp + (size_t)(bt * 64 + q) * DEMB + h * 64 + dg * 16;
#pragma unroll
        for (int j = 0; j < 16; j++) op[j] = f2bf(O[j] / L);
    }
}

// ------------------------------ launcher -----------------------------------
extern "C" void kernel_launch(void* const* d_in, const int* in_sizes, int n_in,
                              void* d_out, int out_size, void* d_ws, size_t ws_size,
                              hipStream_t stream) {
    const float* src   = (const float*)d_in[0];
    const float* ltn   = (const float*)d_in[1];
    const float* g_src = (const float*)d_in[2];
    const float* b_src = (const float*)d_in[3];
    const float* g_ltn = (const float*)d_in[4];
    const float* b_ltn = (const float*)d_in[5];
    const float* Wq    = (const float*)d_in[6];
    const float* Wkv   = (const float*)d_in[7];
    const float* Wo    = (const float*)d_in[8];
    float* out = (float*)d_out;

    char* ws = (char*)d_ws;
    size_t off = 0;
    auto alloc = [&](size_t bytes) -> void* {
        void* p = ws + off;
        off += (bytes + 255) & ~(size_t)255;
        return p;
    };
    ushort* ctx  = (ushort*)alloc((size_t)MROWS * DIMK * 2);   // 101.4 MB
    ushort* qin  = (ushort*)alloc((size_t)512 * DIMK * 2);
    ushort* WkvT = (ushort*)alloc((size_t)1024 * DIMK * 2);
    ushort* WqT  = (ushort*)alloc((size_t)512 * DIMK * 2);
    ushort* WoT  = (ushort*)alloc((size_t)768 * DEMB * 2);
    ushort* kvb  = (ushort*)alloc((size_t)MROWS * 1024 * 2);   // 135.3 MB
    ushort* qfb  = (ushort*)alloc((size_t)512 * DEMB * 2);
    ushort* outp = (ushort*)alloc((size_t)512 * DEMB * 2);
    int*    cnt  = (int*)   alloc(64 * sizeof(int));

    // attention partials alias the ctx buffer (dead after the fused GEMM)
    float* Op  = (float*)(void*)ctx;                       // 16.8 MB
    float* mlb = Op + (size_t)64 * NSPLIT * 64 * 64;

    // 1) transposes + layernorm (independent halves, one launch)
    prep_kernel<<<LN_BLOCKS + TR_BLOCKS, 256, 0, stream>>>(
        src, ltn, g_src, b_src, g_ltn, b_ltn, ctx, qin,
        Wkv, Wq, Wo, WkvT, WqT, WoT);

    // 2) KV projection + pre-scaled Q projection + counter zeroing
    gemm_kvq<<<KV_BLOCKS + Q_BLOCKS, 256, 0, stream>>>(
        ctx, WkvT, kvb, qin, WqT, qfb, cnt);

    // 3) attention with fused split-combine
    attn_flash<<<dim3(64, NSPLIT), 256, 0, stream>>>(qfb, kvb, Op, mlb, cnt, outp);

    // 4) output projection (grid 24, 24%8==0 for T1)
    gemm_bt<float><<<dim3(768 / 128, 512 / 128), 256, 0, stream>>>(
        outp, WoT, out, 512, 768, DEMB);
}

// Round 8
// 552.758 us; speedup vs baseline: 1.2898x; 1.2898x over previous
//
#include <hip/hip_runtime.h>
#include <hip/hip_bf16.h>
#include <type_traits>

// ---------------------------------------------------------------------------
// PerceiverAttention on MI355X.
// Pipeline (5 launches):
//   1) prep_kernel   : [fused] LN (grid-strided, 2064 persistent blocks) AND
//                      Wkv/Wq/Wo transposes -> ctx/qin + bf16 weights
//   2) gemm_kvq      : [fused] kv = ctx @ WkvT^T (4128 blk, T1 swizzle) AND
//                      q = 0.125*(qin @ WqT^T) (16 blk tail; 2^-3 EXACT in
//                      bf16 -> attn needs no per-element scale)
//   3) attn_flash    : split-K MFMA flash attention, wave-local softmax
//                      (R6 structure restored: R7's fused-combine/threadfence
//                      + V-reg-prefetch stalled it 26->230us, MfmaUtil 1.5%)
//   4) attn_combine  : merge 16 splits -> outp bf16 [512][512]
//   5) gemm_bt<float>: out = outp @ WoT^T -> f32 d_out [512][768]
// History: 256^2 deep-pipeline ports (R1 185/R2 169/R4 206us) all lost to the
// 128^2 m97 kernel (156us) at K=768. KV GEMM loop frozen. attn path frozen at
// the R6 structure. Residual ledger (R6/R7 cross-check): prep ~250us vs 50us
// roofline -> this round probes block-dispatch overhead via grid-stride.
// ---------------------------------------------------------------------------

#define N_SRC 8192
#define N_LTN 64
#define N_CTX 8256            // per (b,t)
#define NBT 8                 // b*t
#define MROWS 66048           // NBT * N_CTX
#define DIMK 768
#define DEMB 512
#define NSPLIT 16
#define NTILES 65             // ceil(N_CTX / 128)

#define LN_UNITS (MROWS / 4)      // 16512 row-groups of 4
#define LN_GRID  2064             // persistent LN blocks (16512 / 8)
#define TR_BLOCKS 576             // 16 x 12 x 3
#define KV_BLOCKS 4128            // 8 x 516
#define Q_BLOCKS  16              // 4 x 4

typedef short short8 __attribute__((ext_vector_type(8)));
typedef float floatx4 __attribute__((ext_vector_type(4)));
typedef __attribute__((address_space(1))) void gvoid;
typedef __attribute__((address_space(3))) void lvoid;

__device__ inline ushort f2bf(float f) {
    union { float f; unsigned u; } v; v.f = f;
    unsigned u = v.u;
    return (ushort)((u + 0x7fffu + ((u >> 16) & 1u)) >> 16);   // RNE
}

// ------------------- prep: layernorm (strided) + transposes ----------------
// blocks [0, LN_GRID)           : LN, each handles LN_UNITS/LN_GRID = 8 units
//                                 (4 rows/unit, 1 wave/row)
// blocks [LN_GRID, +TR_BLOCKS)  : 64x64 LDS-tiled transpose of Wkv/Wq/Wo
__global__ __launch_bounds__(256) void prep_kernel(
        const float* __restrict__ src, const float* __restrict__ ltn,
        const float* __restrict__ gs, const float* __restrict__ bs,
        const float* __restrict__ gl, const float* __restrict__ bl,
        ushort* __restrict__ ctx, ushort* __restrict__ qin,
        const float* __restrict__ Wkv, const float* __restrict__ Wq,
        const float* __restrict__ Wo, ushort* __restrict__ WkvT,
        ushort* __restrict__ WqT, ushort* __restrict__ WoT) {
    __shared__ ushort tile[64][65];

    if (blockIdx.x < LN_GRID) {
        int lane = threadIdx.x & 63;
        int wrow = threadIdx.x >> 6;
        for (int unit = blockIdx.x; unit < LN_UNITS; unit += LN_GRID) {
            int r = unit * 4 + wrow;
            int bt = r / N_CTX;
            int i = r - bt * N_CTX;
            const float *x, *g, *b;
            int isl = (i >= N_SRC);
            if (!isl) { x = src + ((size_t)bt * N_SRC + i) * DIMK; g = gs; b = bs; }
            else      { x = ltn + ((size_t)bt * N_LTN + (i - N_SRC)) * DIMK; g = gl; b = bl; }
            float4 v[3]; float s = 0.f, s2 = 0.f;
#pragma unroll
            for (int t = 0; t < 3; t++) {
                float4 xv = *(const float4*)(x + t * 256 + lane * 4);
                v[t] = xv;
                s  += xv.x + xv.y + xv.z + xv.w;
                s2 += xv.x * xv.x + xv.y * xv.y + xv.z * xv.z + xv.w * xv.w;
            }
#pragma unroll
            for (int off = 32; off >= 1; off >>= 1) {
                s  += __shfl_xor(s,  off, 64);
                s2 += __shfl_xor(s2, off, 64);
            }
            float mu  = s * (1.0f / 768.0f);
            float var = s2 * (1.0f / 768.0f) - mu * mu;
            float rs  = rsqrtf(var + 1e-5f);
            ushort* crow = ctx + (size_t)r * DIMK;
            ushort* qrow = isl ? (qin + (size_t)(bt * N_LTN + (i - N_SRC)) * DIMK) : nullptr;
#pragma unroll
            for (int t = 0; t < 3; t++) {
                int idx = t * 256 + lane * 4;
                float4 gv = *(const float4*)(g + idx);
                float4 bv = *(const float4*)(b + idx);
                ushort4 u;
                u.x = f2bf((v[t].x - mu) * rs * gv.x + bv.x);
                u.y = f2bf((v[t].y - mu) * rs * gv.y + bv.y);
                u.z = f2bf((v[t].z - mu) * rs * gv.z + bv.z);
                u.w = f2bf((v[t].w - mu) * rs * gv.w + bv.w);
                *(ushort4*)(crow + idx) = u;
                if (isl) *(ushort4*)(qrow + idx) = u;
            }
        }
        return;
    }

    // ---------------- weight transpose ----------------
    int bid2 = blockIdx.x - LN_GRID;     // [0, 576): x 16, y 12, z 3
    int z = bid2 / 192;
    int rem = bid2 - z * 192;
    int by = rem >> 4, bx = rem & 15;
    const float* in; ushort* out; int R, C;
    if (z == 0)      { in = Wkv; out = WkvT; R = 768; C = 1024; }
    else if (z == 1) { in = Wq;  out = WqT;  R = 768; C = 512;  }
    else             { in = Wo;  out = WoT;  R = 512; C = 768;  }
    int C0 = bx * 64, R0 = by * 64;
    if (C0 >= C || R0 >= R) return;      // uniform early-out (before any sync)
    int tc = threadIdx.x & 63, tr4 = threadIdx.x >> 6;
#pragma unroll
    for (int j = 0; j < 16; j++) {
        int r = tr4 + j * 4;
        tile[r][tc] = f2bf(in[(size_t)(R0 + r) * C + C0 + tc]);
    }
    __syncthreads();
#pragma unroll
    for (int j = 0; j < 16; j++) {
        int c = tr4 + j * 4;
        out[(size_t)(C0 + c) * R + R0 + tc] = tile[tc][c];
    }
}

// --------------- fused KV + Q projection GEMM (128^2, K=768) ---------------
// blocks [0, KV_BLOCKS)        : kvb[66048][1024] = ctx @ WkvT^T, T1 swizzle
// blocks [KV_BLOCKS, +Q_BLOCKS): qfb[512][512] = 0.125*(qin @ WqT^T) (tail)
// Single bf16 epilogue path; scl is SGPR-uniform {1.0, 0.125} (x1.0 exact).
__global__ __launch_bounds__(256) void gemm_kvq(
        const ushort* __restrict__ ctx, const ushort* __restrict__ WkvT,
        ushort* __restrict__ kvb, const ushort* __restrict__ qin,
        const ushort* __restrict__ WqT, ushort* __restrict__ qfb) {
    __shared__ ushort lA[128 * 64];
    __shared__ ushort lB[128 * 64];
    int tid = threadIdx.x;
    int lane = tid & 63, wave = tid >> 6;
    int wm = wave >> 1, wn = wave & 1;

    int lin = blockIdx.x;
    const ushort *A, *B;
    ushort* Cp;
    int bm, bn, N;
    float scl;
    if (lin < KV_BLOCKS) {
        int swz = (lin & 7) * (KV_BLOCKS >> 3) + (lin >> 3);   // T1, 4128%8==0
        bn = swz & 7; bm = swz >> 3;                           // 8 col-tiles
        A = ctx; B = WkvT; Cp = kvb; N = 1024; scl = 1.0f;
    } else {
        int l2 = lin - KV_BLOCKS;
        bn = l2 & 3; bm = l2 >> 2;                             // 4 x 4
        A = qin; B = WqT; Cp = qfb; N = 512; scl = 0.125f;     // exact 2^-3
    }
    const int K = DIMK;                                        // 768 for both

    floatx4 acc[4][4];
#pragma unroll
    for (int mi = 0; mi < 4; mi++)
#pragma unroll
        for (int ni = 0; ni < 4; ni++) acc[mi][ni] = (floatx4){0.f, 0.f, 0.f, 0.f};

    int srow = lane >> 3;
    int schunk = (lane & 7) ^ srow;
    int quad = lane >> 4, lr = lane & 15;
    const int kiters = K >> 6;                                 // 12

    for (int kt = 0; kt < kiters; kt++) {
#pragma unroll
        for (int c2 = 0; c2 < 4; c2++) {
            int row = c2 * 32 + wave * 8 + srow;
            const ushort* gpA = A + ((size_t)(bm * 128 + row) * K + kt * 64 + schunk * 8);
            ushort* lpA = lA + (c2 * 32 + wave * 8) * 64 + lane * 8;
            __builtin_amdgcn_global_load_lds((gvoid*)gpA, (lvoid*)lpA, 16, 0, 0);
            const ushort* gpB = B + ((size_t)(bn * 128 + row) * K + kt * 64 + schunk * 8);
            ushort* lpB = lB + (c2 * 32 + wave * 8) * 64 + lane * 8;
            __builtin_amdgcn_global_load_lds((gvoid*)gpB, (lvoid*)lpB, 16, 0, 0);
        }
        __syncthreads();
#pragma unroll
        for (int ks = 0; ks < 2; ks++) {
            short8 av[4], bv[4];
            int slot = ((ks * 4 + quad) ^ (lane & 7)) * 8;
#pragma unroll
            for (int mi = 0; mi < 4; mi++)
                av[mi] = *(const short8*)(lA + (wm * 64 + mi * 16 + lr) * 64 + slot);
#pragma unroll
            for (int ni = 0; ni < 4; ni++)
                bv[ni] = *(const short8*)(lB + (wn * 64 + ni * 16 + lr) * 64 + slot);
#pragma unroll
            for (int mi = 0; mi < 4; mi++)
#pragma unroll
                for (int ni = 0; ni < 4; ni++)
                    acc[mi][ni] = __builtin_amdgcn_mfma_f32_16x16x32_bf16(
                        av[mi], bv[ni], acc[mi][ni], 0, 0, 0);
        }
        __syncthreads();
    }
#pragma unroll
    for (int mi = 0; mi < 4; mi++)
#pragma unroll
        for (int ni = 0; ni < 4; ni++)
#pragma unroll
            for (int r = 0; r < 4; r++) {
                int row = bm * 128 + wm * 64 + mi * 16 + quad * 4 + r;
                int col = bn * 128 + wn * 64 + ni * 16 + lr;
                Cp[(size_t)row * N + col] = f2bf(acc[mi][ni][r] * scl);
            }
}

// ------------------------------- GEMM (128^2) ------------------------------
// Used for the Wo projection (grid 24, 24%8==0 for T1).
template <typename CT>
__global__ __launch_bounds__(256) void gemm_bt(
        const ushort* __restrict__ A, const ushort* __restrict__ B,
        CT* __restrict__ C, int M, int N, int K) {
    __shared__ ushort lA[128 * 64];
    __shared__ ushort lB[128 * 64];
    int tid = threadIdx.x;
    int lane = tid & 63, wave = tid >> 6;
    int wm = wave >> 1, wn = wave & 1;

    int nwg = gridDim.x * gridDim.y;
    int lin = blockIdx.y * gridDim.x + blockIdx.x;
    int swz = (lin & 7) * (nwg >> 3) + (lin >> 3);
    int bn = swz % gridDim.x, bm = swz / gridDim.x;

    floatx4 acc[4][4];
#pragma unroll
    for (int mi = 0; mi < 4; mi++)
#pragma unroll
        for (int ni = 0; ni < 4; ni++) acc[mi][ni] = (floatx4){0.f, 0.f, 0.f, 0.f};

    int srow = lane >> 3;
    int schunk = (lane & 7) ^ srow;
    int quad = lane >> 4, lr = lane & 15;
    const int kiters = K >> 6;

    for (int kt = 0; kt < kiters; kt++) {
#pragma unroll
        for (int c2 = 0; c2 < 4; c2++) {
            int row = c2 * 32 + wave * 8 + srow;
            const ushort* gpA = A + ((size_t)(bm * 128 + row) * K + kt * 64 + schunk * 8);
            ushort* lpA = lA + (c2 * 32 + wave * 8) * 64 + lane * 8;
            __builtin_amdgcn_global_load_lds((gvoid*)gpA, (lvoid*)lpA, 16, 0, 0);
            const ushort* gpB = B + ((size_t)(bn * 128 + row) * K + kt * 64 + schunk * 8);
            ushort* lpB = lB + (c2 * 32 + wave * 8) * 64 + lane * 8;
            __builtin_amdgcn_global_load_lds((gvoid*)gpB, (lvoid*)lpB, 16, 0, 0);
        }
        __syncthreads();
#pragma unroll
        for (int ks = 0; ks < 2; ks++) {
            short8 av[4], bv[4];
            int slot = ((ks * 4 + quad) ^ (lane & 7)) * 8;
#pragma unroll
            for (int mi = 0; mi < 4; mi++)
                av[mi] = *(const short8*)(lA + (wm * 64 + mi * 16 + lr) * 64 + slot);
#pragma unroll
            for (int ni = 0; ni < 4; ni++)
                bv[ni] = *(const short8*)(lB + (wn * 64 + ni * 16 + lr) * 64 + slot);
#pragma unroll
            for (int mi = 0; mi < 4; mi++)
#pragma unroll
                for (int ni = 0; ni < 4; ni++)
                    acc[mi][ni] = __builtin_amdgcn_mfma_f32_16x16x32_bf16(
                        av[mi], bv[ni], acc[mi][ni], 0, 0, 0);
        }
        __syncthreads();
    }
#pragma unroll
    for (int mi = 0; mi < 4; mi++)
#pragma unroll
        for (int ni = 0; ni < 4; ni++)
#pragma unroll
            for (int r = 0; r < 4; r++) {
                int row = bm * 128 + wm * 64 + mi * 16 + quad * 4 + r;
                int col = bn * 128 + wn * 64 + ni * 16 + lr;
                float vv = acc[mi][ni][r];
                if constexpr (std::is_same<CT, ushort>::value)
                    C[(size_t)row * N + col] = f2bf(vv);
                else
                    C[(size_t)row * N + col] = vv;
            }
}

// ------------------------- flash attention (split-K) -----------------------
// R6 structure (verified ~25us): per-tile V loads, 2 __syncthreads per tile,
// separate combine kernel. Micro-wins kept from R7 (numerically verified):
// Q pre-scaled by 0.125 in the GEMM (no per-element scale here), in-place
// accS masking (no sc[] array), direct short8 Q loads.
#define PR 136

__global__ __launch_bounds__(256) void attn_flash(
        const ushort* __restrict__ qfb, const ushort* __restrict__ kvb,
        float* __restrict__ Op, float* __restrict__ ml) {
    __shared__ ushort lK[128 * 64];
    __shared__ ushort lVT[64 * PR];   // [d 0..63][key 0..127]
    __shared__ ushort lP[64 * PR];    // [qrow 0..63][key 0..127], wave-private rows

    int comb = blockIdx.x, split = blockIdx.y;
    int bt = comb >> 3, h = comb & 7;
    int tid = threadIdx.x;
    int w = tid >> 6, lane = tid & 63, quad = lane >> 4, lr = lane & 15;

    const ushort* kptr = kvb + (size_t)bt * N_CTX * 1024 + h * 64;
    const ushort* vptr = kptr + 512;

    short8 qa[2];
    {
        const ushort* p0 = qfb + (size_t)(bt * 64 + w * 16 + lr) * DEMB + h * 64;
        qa[0] = *(const short8*)(p0 + quad * 8);
        qa[1] = *(const short8*)(p0 + 32 + quad * 8);
    }

    floatx4 accO[4];
#pragma unroll
    for (int nt = 0; nt < 4; nt++) accO[nt] = (floatx4){0.f, 0.f, 0.f, 0.f};
    float m_run[4], l_run[4];
#pragma unroll
    for (int r = 0; r < 4; r++) { m_run[r] = -1e30f; l_run[r] = 0.f; }

    for (int t = split; t < NTILES; t += NSPLIT) {
        int kbase = t * 128;
        __syncthreads();   // prev-iter lK/lVT readers done before restaging

        // ---- stage K (global_load_lds, swizzled) ----
#pragma unroll
        for (int c2 = 0; c2 < 4; c2++) {
            int jloc = w * 32 + c2 * 8 + (lane >> 3);
            int chunk = (lane & 7) ^ ((lane >> 3) & 7);
            int jg = kbase + jloc; if (jg > N_CTX - 1) jg = N_CTX - 1;  // clamp tail
            const ushort* gp = kptr + (size_t)jg * 1024 + chunk * 8;
            ushort* lp = lK + (w * 32 + c2 * 8) * 64 + lane * 8;
            __builtin_amdgcn_global_load_lds((gvoid*)gp, (lvoid*)lp, 16, 0, 0);
        }

        // ---- stage V^T via pack-transpose (thread: key-pair x 16 dims) ----
        {
            int k0 = kbase + lane * 2;
            bool valid = (k0 + 1) < N_CTX;
            int k0c = valid ? k0 : (N_CTX - 2);
            const ushort* r0 = vptr + (size_t)k0c * 1024 + w * 16;
            const ushort* r1 = r0 + 1024;
            uint4 a0 = *(const uint4*)r0;
            uint4 a1 = *(const uint4*)(r0 + 8);
            uint4 b0 = *(const uint4*)r1;
            uint4 b1 = *(const uint4*)(r1 + 8);
            if (!valid) {
                a0 = make_uint4(0, 0, 0, 0); a1 = a0; b0 = a0; b1 = a0;
            }
            unsigned av8[8] = {a0.x, a0.y, a0.z, a0.w, a1.x, a1.y, a1.z, a1.w};
            unsigned bv8[8] = {b0.x, b0.y, b0.z, b0.w, b1.x, b1.y, b1.z, b1.w};
#pragma unroll
            for (int i = 0; i < 8; i++) {
                unsigned la = av8[i] & 0xffffu, ha = av8[i] >> 16;
                unsigned lb = bv8[i] & 0xffffu, hb = bv8[i] >> 16;
                *(unsigned*)(lVT + (w * 16 + 2 * i) * PR + lane * 2)     = la | (lb << 16);
                *(unsigned*)(lVT + (w * 16 + 2 * i + 1) * PR + lane * 2) = ha | (hb << 16);
            }
        }
        __syncthreads();   // staging complete

        floatx4 accS[8];
#pragma unroll
        for (int nt = 0; nt < 8; nt++) accS[nt] = (floatx4){0.f, 0.f, 0.f, 0.f};
#pragma unroll
        for (int kc = 0; kc < 2; kc++) {
#pragma unroll
            for (int nt = 0; nt < 8; nt++) {
                int kr = nt * 16 + lr;
                int slot = (kc * 4 + quad) ^ (kr & 7);
                short8 bv = *(const short8*)(lK + kr * 64 + slot * 8);
                accS[nt] = __builtin_amdgcn_mfma_f32_16x16x32_bf16(
                    qa[kc], bv, accS[nt], 0, 0, 0);
            }
        }

        // ---- mask (in place) + row max ----
        float tmax[4] = {-1e30f, -1e30f, -1e30f, -1e30f};
#pragma unroll
        for (int nt = 0; nt < 8; nt++) {
            bool vk = (kbase + nt * 16 + lr) < N_CTX;
#pragma unroll
            for (int r = 0; r < 4; r++) {
                float s = vk ? accS[nt][r] : -1e30f;
                accS[nt][r] = s;
                tmax[r] = fmaxf(tmax[r], s);
            }
        }
#pragma unroll
        for (int r = 0; r < 4; r++) {
#pragma unroll
            for (int d = 1; d < 16; d <<= 1) tmax[r] = fmaxf(tmax[r], __shfl_xor(tmax[r], d, 64));
        }
        float alpha[4], lsum[4];
#pragma unroll
        for (int r = 0; r < 4; r++) {
            float mn = fmaxf(m_run[r], tmax[r]);
            alpha[r] = __expf(m_run[r] - mn);
            m_run[r] = mn;
            lsum[r] = 0.f;
        }

#pragma unroll
        for (int nt = 0; nt < 8; nt++) {
#pragma unroll
            for (int r = 0; r < 4; r++) {
                float p = __expf(accS[nt][r] - m_run[r]);
                lsum[r] += p;
                lP[(w * 16 + quad * 4 + r) * PR + nt * 16 + lr] = f2bf(p);
            }
        }
#pragma unroll
        for (int r = 0; r < 4; r++) {
#pragma unroll
            for (int d = 1; d < 16; d <<= 1) lsum[r] += __shfl_xor(lsum[r], d, 64);
            l_run[r] = l_run[r] * alpha[r] + lsum[r];
        }
#pragma unroll
        for (int nt = 0; nt < 4; nt++) {
            accO[nt][0] *= alpha[0]; accO[nt][1] *= alpha[1];
            accO[nt][2] *= alpha[2]; accO[nt][3] *= alpha[3];
        }

        short8 av[4];
#pragma unroll
        for (int kc = 0; kc < 4; kc++)
            av[kc] = *(const short8*)(lP + (w * 16 + lr) * PR + kc * 32 + quad * 8);
#pragma unroll
        for (int nt = 0; nt < 4; nt++)
#pragma unroll
            for (int kc = 0; kc < 4; kc++) {
                short8 bv = *(const short8*)(lVT + (nt * 16 + lr) * PR + kc * 32 + quad * 8);
                accO[nt] = __builtin_amdgcn_mfma_f32_16x16x32_bf16(av[kc], bv, accO[nt], 0, 0, 0);
            }
    }

    float* opb = Op + (size_t)(comb * NSPLIT + split) * 64 * 64;
#pragma unroll
    for (int nt = 0; nt < 4; nt++)
#pragma unroll
        for (int r = 0; r < 4; r++)
            opb[(w * 16 + quad * 4 + r) * 64 + nt * 16 + lr] = accO[nt][r];
    if (lr == 0) {
#pragma unroll
        for (int r = 0; r < 4; r++) {
            int row = w * 16 + quad * 4 + r;
            float* mlp = ml + ((size_t)(comb * NSPLIT + split) * 64 + row) * 2;
            mlp[0] = m_run[r]; mlp[1] = l_run[r];
        }
    }
}

__global__ __launch_bounds__(64) void attn_combine(
        const float* __restrict__ Op, const float* __restrict__ ml,
        ushort* __restrict__ outp) {
    int bx = blockIdx.x;
    int comb = bx >> 6, q = bx & 63;
    int bt = comb >> 3, h = comb & 7;
    int d = threadIdx.x;
    float M = -1e30f;
    for (int s = 0; s < NSPLIT; s++)
        M = fmaxf(M, ml[((size_t)(comb * NSPLIT + s) * 64 + q) * 2]);
    float L = 0.f, O = 0.f;
    for (int s = 0; s < NSPLIT; s++) {
        const float* p = ml + ((size_t)(comb * NSPLIT + s) * 64 + q) * 2;
        float wgt = __expf(p[0] - M);
        L = fmaf(wgt, p[1], L);
        O = fmaf(wgt, Op[((size_t)(comb * NSPLIT + s) * 64 + q) * 64 + d], O);
    }
    outp[(size_t)(bt * 64 + q) * DEMB + h * 64 + d] = f2bf(O / L);
}

// ------------------------------ launcher -----------------------------------
extern "C" void kernel_launch(void* const* d_in, const int* in_sizes, int n_in,
                              void* d_out, int out_size, void* d_ws, size_t ws_size,
                              hipStream_t stream) {
    const float* src   = (const float*)d_in[0];
    const float* ltn   = (const float*)d_in[1];
    const float* g_src = (const float*)d_in[2];
    const float* b_src = (const float*)d_in[3];
    const float* g_ltn = (const float*)d_in[4];
    const float* b_ltn = (const float*)d_in[5];
    const float* Wq    = (const float*)d_in[6];
    const float* Wkv   = (const float*)d_in[7];
    const float* Wo    = (const float*)d_in[8];
    float* out = (float*)d_out;

    char* ws = (char*)d_ws;
    size_t off = 0;
    auto alloc = [&](size_t bytes) -> void* {
        void* p = ws + off;
        off += (bytes + 255) & ~(size_t)255;
        return p;
    };
    ushort* ctx  = (ushort*)alloc((size_t)MROWS * DIMK * 2);   // 101.4 MB
    ushort* qin  = (ushort*)alloc((size_t)512 * DIMK * 2);
    ushort* WkvT = (ushort*)alloc((size_t)1024 * DIMK * 2);
    ushort* WqT  = (ushort*)alloc((size_t)512 * DIMK * 2);
    ushort* WoT  = (ushort*)alloc((size_t)768 * DEMB * 2);
    ushort* kvb  = (ushort*)alloc((size_t)MROWS * 1024 * 2);   // 135.3 MB
    ushort* qfb  = (ushort*)alloc((size_t)512 * DEMB * 2);
    ushort* outp = (ushort*)alloc((size_t)512 * DEMB * 2);

    // attention partials alias the ctx buffer (dead after the fused GEMM)
    float* Op  = (float*)(void*)ctx;                       // 16.8 MB
    float* mlb = Op + (size_t)64 * NSPLIT * 64 * 64;

    // 1) layernorm (grid-strided) + weight transposes
    prep_kernel<<<LN_GRID + TR_BLOCKS, 256, 0, stream>>>(
        src, ltn, g_src, b_src, g_ltn, b_ltn, ctx, qin,
        Wkv, Wq, Wo, WkvT, WqT, WoT);

    // 2) KV projection + pre-scaled Q projection
    gemm_kvq<<<KV_BLOCKS + Q_BLOCKS, 256, 0, stream>>>(
        ctx, WkvT, kvb, qin, WqT, qfb);

    // 3-4) attention (R6 structure) + combine
    attn_flash<<<dim3(64, NSPLIT), 256, 0, stream>>>(qfb, kvb, Op, mlb);
    attn_combine<<<4096, 64, 0, stream>>>(Op, mlb, outp);

    // 5) output projection (grid 24, 24%8==0 for T1)
    gemm_bt<float><<<dim3(768 / 128, 512 / 128), 256, 0, stream>>>(
        outp, WoT, out, 512, 768, DEMB);
}